// Round 1
// baseline (292.069 us; speedup 1.0000x reference)
//
#include <hip/hip_runtime.h>
#include <math.h>

#define B_TOT 1024
#define IN_N  128   // iN
#define IN_D  16    // iD
#define NCAP  32    // N
#define DCAP  32    // D
#define BT    8     // batches per block
#define THREADS 512

// ---------------------------------------------------------------------------
// Kernel A: per block = (one n, 8 b's). Compute u tiles (in registers),
// usum via LDS reduction, logits = (u . usum)/sqrt(D) -> ws.
// ---------------------------------------------------------------------------
__global__ __launch_bounds__(THREADS, 2)
void kA_logits(const float* __restrict__ x, const float* __restrict__ W,
               float* __restrict__ logits /* [B][N][iN] */) {
    const int bid   = blockIdx.x;
    const int n     = bid >> 7;          // 128 btiles per n; consecutive blocks share n
    const int b0    = (bid & 127) * BT;
    const int t     = threadIdx.x;
    const int z     = t & 31;            // output dim
    const int jb    = t >> 5;            // 0..15 j-group

    __shared__ __align__(16) float x_lds[BT][IN_N * IN_D];  // 64 KB
    __shared__ __align__(16) float u_lds[IN_N][36];         // 18 KB (pad 36, conflict-free)
    __shared__ float red[BT][16][32];                        // 16 KB
    __shared__ float usum_f[BT][32];                         // 1 KB

    // stage x[b0..b0+7] into LDS (coalesced float4)
    {
        const float4* src = (const float4*)(x + (size_t)b0 * (IN_N * IN_D));
        float4* dst = (float4*)&x_lds[0][0];
        for (int k = t; k < BT * IN_N * IN_D / 4; k += THREADS) dst[k] = src[k];
    }
    __syncthreads();

    float usum_part[BT];
    float u_reg[BT][8];
#pragma unroll
    for (int bl = 0; bl < BT; ++bl) usum_part[bl] = 0.f;

    const float* Wn = W + (size_t)n * IN_N * IN_D * DCAP;

#pragma unroll
    for (int jit = 0; jit < 8; ++jit) {
        const int j = jb + 16 * jit;
        const float* wp = Wn + (size_t)j * IN_D * DCAP + z;   // stride DCAP over i
        float wv[IN_D];
#pragma unroll
        for (int i = 0; i < IN_D; ++i) wv[i] = wp[i * DCAP];  // coalesced across z
#pragma unroll
        for (int bl = 0; bl < BT; ++bl) {
            const float4* xr = (const float4*)&x_lds[bl][j * IN_D];
            float4 a0 = xr[0], a1 = xr[1], a2 = xr[2], a3 = xr[3];
            float acc;
            acc  = a0.x * wv[0]  + a0.y * wv[1]  + a0.z * wv[2]  + a0.w * wv[3];
            acc += a1.x * wv[4]  + a1.y * wv[5]  + a1.z * wv[6]  + a1.w * wv[7];
            acc += a2.x * wv[8]  + a2.y * wv[9]  + a2.z * wv[10] + a2.w * wv[11];
            acc += a3.x * wv[12] + a3.y * wv[13] + a3.z * wv[14] + a3.w * wv[15];
            u_reg[bl][jit] = acc;
            usum_part[bl] += acc;
        }
    }

    // reduce usum over the 16 j-groups
#pragma unroll
    for (int bl = 0; bl < BT; ++bl) red[bl][jb][z] = usum_part[bl];
    __syncthreads();
    if (t < BT * 32) {
        const int bl = t >> 5, zz = t & 31;
        float s = 0.f;
#pragma unroll
        for (int g = 0; g < 16; ++g) s += red[bl][g][zz];
        usum_f[bl][zz] = s;
    }
    __syncthreads();

    const float rsqD = 0.17677669529663689f;  // 1/sqrt(32)
#pragma unroll
    for (int bl = 0; bl < BT; ++bl) {
        // scatter this bl's u tile into LDS (2-way bank alias only)
#pragma unroll
        for (int jit = 0; jit < 8; ++jit) u_lds[jb + 16 * jit][z] = u_reg[bl][jit];
        __syncthreads();
        // logits: 4 threads per j, each dots 8 z's, combine via shfl
        {
            const int j = t >> 2;   // 0..127
            const int q = t & 3;
            float p = 0.f;
#pragma unroll
            for (int k = 0; k < 8; ++k) {
                const int zz = q * 8 + k;
                p += u_lds[j][zz] * usum_f[bl][zz];
            }
            p += __shfl_xor(p, 1);
            p += __shfl_xor(p, 2);
            if (q == 0)
                logits[((size_t)(b0 + bl) * NCAP + n) * IN_N + j] = p * rsqD;
        }
        __syncthreads();
    }
}

// ---------------------------------------------------------------------------
// Kernel B: softmax over n per (b,j), in-place in ws; then + bias[n,j].
// ---------------------------------------------------------------------------
__global__ void kB_softmax(const float* __restrict__ bias, float* __restrict__ lc) {
    const int idx = blockIdx.x * blockDim.x + threadIdx.x;  // (b, j)
    if (idx >= B_TOT * IN_N) return;
    const int b = idx >> 7;
    const int j = idx & 127;
    float v[NCAP];
    float m = -1e30f;
#pragma unroll
    for (int n = 0; n < NCAP; ++n) {
        v[n] = lc[((size_t)b * NCAP + n) * IN_N + j];
        m = fmaxf(m, v[n]);
    }
    float s = 0.f;
#pragma unroll
    for (int n = 0; n < NCAP; ++n) { v[n] = __expf(v[n] - m); s += v[n]; }
    const float inv = 1.f / s;
#pragma unroll
    for (int n = 0; n < NCAP; ++n)
        lc[((size_t)b * NCAP + n) * IN_N + j] = v[n] * inv + bias[n * IN_N + j];
}

// ---------------------------------------------------------------------------
// Kernel C: recompute u, s = sum_j c*u, squash, write out.
// ---------------------------------------------------------------------------
__global__ __launch_bounds__(THREADS, 2)
void kC_out(const float* __restrict__ x, const float* __restrict__ W,
            const float* __restrict__ c, float* __restrict__ out) {
    const int bid = blockIdx.x;
    const int n   = bid >> 7;
    const int b0  = (bid & 127) * BT;
    const int t   = threadIdx.x;
    const int z   = t & 31;
    const int jb  = t >> 5;

    __shared__ __align__(16) float x_lds[BT][IN_N * IN_D];  // 64 KB
    __shared__ float c_lds[BT][IN_N];                        // 4 KB
    __shared__ float red[BT][16][32];                        // 16 KB

    {
        const float4* src = (const float4*)(x + (size_t)b0 * (IN_N * IN_D));
        float4* dst = (float4*)&x_lds[0][0];
        for (int k = t; k < BT * IN_N * IN_D / 4; k += THREADS) dst[k] = src[k];
    }
    for (int k = t; k < BT * IN_N; k += THREADS) {
        const int bl = k >> 7, j = k & 127;
        c_lds[bl][j] = c[((size_t)(b0 + bl) * NCAP + n) * IN_N + j];
    }
    __syncthreads();

    float s_part[BT];
#pragma unroll
    for (int bl = 0; bl < BT; ++bl) s_part[bl] = 0.f;

    const float* Wn = W + (size_t)n * IN_N * IN_D * DCAP;

#pragma unroll
    for (int jit = 0; jit < 8; ++jit) {
        const int j = jb + 16 * jit;
        const float* wp = Wn + (size_t)j * IN_D * DCAP + z;
        float wv[IN_D];
#pragma unroll
        for (int i = 0; i < IN_D; ++i) wv[i] = wp[i * DCAP];
#pragma unroll
        for (int bl = 0; bl < BT; ++bl) {
            const float4* xr = (const float4*)&x_lds[bl][j * IN_D];
            float4 a0 = xr[0], a1 = xr[1], a2 = xr[2], a3 = xr[3];
            float acc;
            acc  = a0.x * wv[0]  + a0.y * wv[1]  + a0.z * wv[2]  + a0.w * wv[3];
            acc += a1.x * wv[4]  + a1.y * wv[5]  + a1.z * wv[6]  + a1.w * wv[7];
            acc += a2.x * wv[8]  + a2.y * wv[9]  + a2.z * wv[10] + a2.w * wv[11];
            acc += a3.x * wv[12] + a3.y * wv[13] + a3.z * wv[14] + a3.w * wv[15];
            s_part[bl] += acc * c_lds[bl][j];
        }
    }

#pragma unroll
    for (int bl = 0; bl < BT; ++bl) red[bl][jb][z] = s_part[bl];
    __syncthreads();

    if (t < BT * 32) {
        const int bl = t >> 5, zz = t & 31;
        float s = 0.f;
#pragma unroll
        for (int g = 0; g < 16; ++g) s += red[bl][g][zz];
        // squash: norm over the 32 z's (lanes zz within a 32-group)
        float nrm2 = s * s;
        nrm2 += __shfl_xor(nrm2, 1);
        nrm2 += __shfl_xor(nrm2, 2);
        nrm2 += __shfl_xor(nrm2, 4);
        nrm2 += __shfl_xor(nrm2, 8);
        nrm2 += __shfl_xor(nrm2, 16);
        const float nn = sqrtf(nrm2);
        const float f  = (1.f - 1.f / (__expf(nn) + 1e-20f)) / (nn + 1e-20f);
        out[((size_t)(b0 + bl) * NCAP + n) * DCAP + zz] = s * f;
    }
}

// ---------------------------------------------------------------------------
extern "C" void kernel_launch(void* const* d_in, const int* in_sizes, int n_in,
                              void* d_out, int out_size, void* d_ws, size_t ws_size,
                              hipStream_t stream) {
    const float* x    = (const float*)d_in[0];   // [1024,128,16]
    const float* W    = (const float*)d_in[1];   // [32,128,16,32]
    const float* bias = (const float*)d_in[2];   // [32,128,1]
    float* out = (float*)d_out;                  // [1024,32,32]
    float* lc  = (float*)d_ws;                   // logits/c scratch: 16.78 MB

    const int nblocks = NCAP * (B_TOT / BT);     // 4096
    kA_logits<<<nblocks, THREADS, 0, stream>>>(x, W, lc);
    kB_softmax<<<(B_TOT * IN_N) / 256, 256, 0, stream>>>(bias, lc);
    kC_out<<<nblocks, THREADS, 0, stream>>>(x, W, lc, out);
}

// Round 2
// 92.996 us; speedup vs baseline: 3.1407x; 3.1407x over previous
//
#include <hip/hip_runtime.h>
#include <math.h>

#define B_TOT 1024
#define IN_N  128
#define IN_D  16
#define NCAP  32
#define DCAP  32

typedef __attribute__((ext_vector_type(8)))  short bf16x8;
typedef __attribute__((ext_vector_type(16))) float f32x16;
typedef unsigned int  uint_;
typedef unsigned short ushort_;

__device__ __forceinline__ uint_ cvt_pk_bf16(float lo, float hi) {
    uint_ r;
    asm("v_cvt_pk_bf16_f32 %0, %1, %2" : "=v"(r) : "v"(lo), "v"(hi));
    return r;
}
__device__ __forceinline__ float bf16_to_f(ushort_ h) {
    return __uint_as_float(((uint_)h) << 16);
}

// ---------------------------------------------------------------------------
// prep_x: x[b][j][i] f32 -> XW[(j*2+ib)*1024 + b][e], e=0..7 bf16 (i = ib*8+e)
// ---------------------------------------------------------------------------
__global__ __launch_bounds__(256)
void prep_x(const float* __restrict__ x, ushort_* __restrict__ XW) {
    const int m  = blockIdx.x * 256 + threadIdx.x;  // 262144 = 256 * 1024
    const int b  = m & 1023;
    const int jb2 = m >> 10;                        // j*2+ib
    const int j  = jb2 >> 1, ib = jb2 & 1;
    const float* p = x + ((size_t)(b * IN_N + j) * IN_D + ib * 8);
    float4 f0 = ((const float4*)p)[0];
    float4 f1 = ((const float4*)p)[1];
    uint4 o;
    o.x = cvt_pk_bf16(f0.x, f0.y);
    o.y = cvt_pk_bf16(f0.z, f0.w);
    o.z = cvt_pk_bf16(f1.x, f1.y);
    o.w = cvt_pk_bf16(f1.z, f1.w);
    *(uint4*)(XW + (size_t)m * 8) = o;
}

// ---------------------------------------------------------------------------
// prep_w: W[n][j][i][z] f32 -> WT[((n*128+j)*32 + z)*16 + i] bf16
// ---------------------------------------------------------------------------
__global__ __launch_bounds__(256)
void prep_w(const float* __restrict__ W, ushort_* __restrict__ WT) {
    const int q  = blockIdx.x * 256 + threadIdx.x;  // 131072
    const int z  = q & 31;
    const int nj = q >> 5;
    const float* p = W + (size_t)nj * (IN_D * DCAP) + z;
    float f[16];
#pragma unroll
    for (int i = 0; i < 16; ++i) f[i] = p[i * 32];
    uint4 lo, hi;
    lo.x = cvt_pk_bf16(f[0],  f[1]);  lo.y = cvt_pk_bf16(f[2],  f[3]);
    lo.z = cvt_pk_bf16(f[4],  f[5]);  lo.w = cvt_pk_bf16(f[6],  f[7]);
    hi.x = cvt_pk_bf16(f[8],  f[9]);  hi.y = cvt_pk_bf16(f[10], f[11]);
    hi.z = cvt_pk_bf16(f[12], f[13]); hi.w = cvt_pk_bf16(f[14], f[15]);
    uint4* dst = (uint4*)(WT + (size_t)q * 16);
    dst[0] = lo; dst[1] = hi;
}

// ---------------------------------------------------------------------------
// kA: per block (n, 32-batch tile); 2 waves split j-range. MFMA u-tiles with
// z as M-axis, b as N-axis. Phase 1: usum via K=2048 chained MFMAs. Phase 2:
// per-j u tile (zero acc) dotted with usum -> logits (bf16) -> LC[n][j][b].
// ---------------------------------------------------------------------------
__global__ __launch_bounds__(128, 2)
void kA(const ushort_* __restrict__ XW, const ushort_* __restrict__ WT,
        ushort_* __restrict__ LC) {
    const int bid = blockIdx.x;          // 1024 = 32 n * 32 btiles
    const int n   = bid >> 5;
    const int cb0 = (bid & 31) * 32;
    const int t   = threadIdx.x;
    const int wv  = t >> 6;
    const int l   = t & 63;
    const int lo5 = l & 31;
    const int hi  = l >> 5;

    __shared__ float xch[2][16 * 64];    // 8 KB

    // A-frag: WT[((n*128+j)*32 + z)*16 + i], z=lo5, i=hi*8+e  -> +j*512 elems
    // B-frag: XW[((j*2+hi)*1024 + b)*8 + e], b=cb0+lo5        -> +j*16384 elems
    const ushort_* aBase = WT + ((size_t)(n * IN_N) * 32 + lo5) * 16 + (size_t)hi * 8;
    const ushort_* bBase = XW + ((size_t)hi * 1024 + cb0 + lo5) * 8;

    const int jbeg = wv * 64;

    f32x16 usA, usB;
#pragma unroll
    for (int r = 0; r < 16; ++r) { usA[r] = 0.f; usB[r] = 0.f; }

    for (int j = jbeg; j < jbeg + 64; j += 2) {
        bf16x8 a0 = *(const bf16x8*)(aBase + (size_t)j * 512);
        bf16x8 x0 = *(const bf16x8*)(bBase + (size_t)j * 16384);
        bf16x8 a1 = *(const bf16x8*)(aBase + (size_t)(j + 1) * 512);
        bf16x8 x1 = *(const bf16x8*)(bBase + (size_t)(j + 1) * 16384);
        usA = __builtin_amdgcn_mfma_f32_32x32x16_bf16(a0, x0, usA, 0, 0, 0);
        usB = __builtin_amdgcn_mfma_f32_32x32x16_bf16(a1, x1, usB, 0, 0, 0);
    }
#pragma unroll
    for (int r = 0; r < 16; ++r) usA[r] += usB[r];

    // cross-wave usum combine
#pragma unroll
    for (int r = 0; r < 16; ++r) xch[wv][r * 64 + l] = usA[r];
    __syncthreads();
    f32x16 us;
#pragma unroll
    for (int r = 0; r < 16; ++r) us[r] = usA[r] + xch[1 - wv][r * 64 + l];

    const float rsqD = 0.17677669529663689f;  // 1/sqrt(32)

    for (int j = jbeg; j < jbeg + 64; ++j) {
        bf16x8 af = *(const bf16x8*)(aBase + (size_t)j * 512);
        bf16x8 xf = *(const bf16x8*)(bBase + (size_t)j * 16384);
        f32x16 u;
#pragma unroll
        for (int r = 0; r < 16; ++r) u[r] = 0.f;
        u = __builtin_amdgcn_mfma_f32_32x32x16_bf16(af, xf, u, 0, 0, 0);
        float p0 = u[0] * us[0], p1 = u[1] * us[1];
        float p2 = u[2] * us[2], p3 = u[3] * us[3];
#pragma unroll
        for (int r = 4; r < 16; r += 4) {
            p0 = fmaf(u[r],     us[r],     p0);
            p1 = fmaf(u[r + 1], us[r + 1], p1);
            p2 = fmaf(u[r + 2], us[r + 2], p2);
            p3 = fmaf(u[r + 3], us[r + 3], p3);
        }
        float p = (p0 + p1) + (p2 + p3);
        p += __shfl_xor(p, 32);
        p *= rsqD;
        if (l < 32) {
            uint_ pk = cvt_pk_bf16(p, p);
            LC[(size_t)(n * IN_N + j) * 1024 + cb0 + lo5] = (ushort_)(pk & 0xffffu);
        }
    }
}

// ---------------------------------------------------------------------------
// kB: softmax over n per (b,j) on bf16 logits in LC, + bias, write back bf16.
// ---------------------------------------------------------------------------
__global__ __launch_bounds__(256)
void kB(const float* __restrict__ bias, ushort_* __restrict__ LC) {
    const int t = blockIdx.x * 256 + threadIdx.x;  // 131072 = 128 j * 1024 b
    const int b = t & 1023;
    const int j = t >> 10;
    float v[NCAP];
    float m = -1e30f;
#pragma unroll
    for (int n = 0; n < NCAP; ++n) {
        v[n] = bf16_to_f(LC[(size_t)(n * IN_N + j) * 1024 + b]);
        m = fmaxf(m, v[n]);
    }
    float s = 0.f;
#pragma unroll
    for (int n = 0; n < NCAP; ++n) { v[n] = __expf(v[n] - m); s += v[n]; }
    const float inv = 1.f / s;
#pragma unroll
    for (int n = 0; n < NCAP; ++n) {
        float c = v[n] * inv + bias[n * IN_N + j];
        uint_ pk = cvt_pk_bf16(c, c);
        LC[(size_t)(n * IN_N + j) * 1024 + b] = (ushort_)(pk & 0xffffu);
    }
}

// ---------------------------------------------------------------------------
// kC: s[b,n,z] = sum_j c[b,n,j] * u[b,n,j,z]; c applied per-lane (col=b) in
// fp32; cross-wave combine; squash; store.
// ---------------------------------------------------------------------------
__global__ __launch_bounds__(128, 2)
void kC(const ushort_* __restrict__ XW, const ushort_* __restrict__ WT,
        const ushort_* __restrict__ LC, float* __restrict__ out) {
    const int bid = blockIdx.x;
    const int n   = bid >> 5;
    const int cb0 = (bid & 31) * 32;
    const int t   = threadIdx.x;
    const int wv  = t >> 6;
    const int l   = t & 63;
    const int lo5 = l & 31;
    const int hi  = l >> 5;

    __shared__ float xch[2][16 * 64];

    const ushort_* aBase = WT + ((size_t)(n * IN_N) * 32 + lo5) * 16 + (size_t)hi * 8;
    const ushort_* bBase = XW + ((size_t)hi * 1024 + cb0 + lo5) * 8;
    const ushort_* cBase = LC + (size_t)(n * IN_N) * 1024 + cb0 + lo5;

    f32x16 s;
#pragma unroll
    for (int r = 0; r < 16; ++r) s[r] = 0.f;

    const int jbeg = wv * 64;
    for (int j = jbeg; j < jbeg + 64; ++j) {
        bf16x8 af = *(const bf16x8*)(aBase + (size_t)j * 512);
        bf16x8 xf = *(const bf16x8*)(bBase + (size_t)j * 16384);
        const float c = bf16_to_f(cBase[(size_t)j * 1024]);
        f32x16 u;
#pragma unroll
        for (int r = 0; r < 16; ++r) u[r] = 0.f;
        u = __builtin_amdgcn_mfma_f32_32x32x16_bf16(af, xf, u, 0, 0, 0);
#pragma unroll
        for (int r = 0; r < 16; ++r) s[r] = fmaf(c, u[r], s[r]);
    }

#pragma unroll
    for (int r = 0; r < 16; ++r) xch[wv][r * 64 + l] = s[r];
    __syncthreads();

    if (wv == 0) {
#pragma unroll
        for (int r = 0; r < 16; ++r) s[r] += xch[1][r * 64 + l];
        float q0 = s[0] * s[0], q1 = s[1] * s[1];
        float q2 = s[2] * s[2], q3 = s[3] * s[3];
#pragma unroll
        for (int r = 4; r < 16; r += 4) {
            q0 = fmaf(s[r],     s[r],     q0);
            q1 = fmaf(s[r + 1], s[r + 1], q1);
            q2 = fmaf(s[r + 2], s[r + 2], q2);
            q3 = fmaf(s[r + 3], s[r + 3], q3);
        }
        float q = (q0 + q1) + (q2 + q3);
        q += __shfl_xor(q, 32);                 // add other half's 16 z's
        const float nn = sqrtf(q);
        const float f  = (1.f - 1.f / (__expf(nn) + 1e-20f)) / (nn + 1e-20f);
        // lane (lo5,hi), reg r -> z = (r&3) + 8*(r>>2) + 4*hi
        float* op = out + ((size_t)(cb0 + lo5) * NCAP + n) * DCAP + hi * 4;
#pragma unroll
        for (int g = 0; g < 4; ++g) {
            float4 v4 = { s[g * 4 + 0] * f, s[g * 4 + 1] * f,
                          s[g * 4 + 2] * f, s[g * 4 + 3] * f };
            *(float4*)(op + g * 8) = v4;
        }
    }
}

// ---------------------------------------------------------------------------
extern "C" void kernel_launch(void* const* d_in, const int* in_sizes, int n_in,
                              void* d_out, int out_size, void* d_ws, size_t ws_size,
                              hipStream_t stream) {
    const float* x    = (const float*)d_in[0];   // [1024,128,16]
    const float* W    = (const float*)d_in[1];   // [32,128,16,32]
    const float* bias = (const float*)d_in[2];   // [32,128,1]
    float* out = (float*)d_out;                  // [1024,32,32]

    char* ws = (char*)d_ws;
    ushort_* XW = (ushort_*)ws;                       // 4 MB bf16 x, relaid
    ushort_* WT = (ushort_*)(ws + (4u << 20));        // 4 MB bf16 W^T
    ushort_* LC = (ushort_*)(ws + (8u << 20));        // 8 MB bf16 logits/c

    prep_x<<<1024, 256, 0, stream>>>(x, XW);
    prep_w<<<512, 256, 0, stream>>>(W, WT);
    kA<<<1024, 128, 0, stream>>>(XW, WT, LC);
    kB<<<512, 256, 0, stream>>>(bias, LC);
    kC<<<1024, 128, 0, stream>>>(XW, WT, LC, out);
}

// Round 3
// 59.278 us; speedup vs baseline: 4.9271x; 1.5688x over previous
//
#include <hip/hip_runtime.h>
#include <math.h>

#define B_TOT 1024
#define IN_N  128
#define IN_D  16
#define NCAP  32
#define DCAP  32

typedef __attribute__((ext_vector_type(8)))  short bf16x8;
typedef __attribute__((ext_vector_type(16))) float f32x16;
typedef unsigned int  uint_;
typedef unsigned short ushort_;

__device__ __forceinline__ uint_ cvt_pk_bf16(float lo, float hi) {
    uint_ r;
    asm("v_cvt_pk_bf16_f32 %0, %1, %2" : "=v"(r) : "v"(lo), "v"(hi));
    return r;
}
__device__ __forceinline__ float bf16_to_f(ushort_ h) {
    return __uint_as_float(((uint_)h) << 16);
}

// ---------------------------------------------------------------------------
// prep (fused): blocks [0,512): W[n][j][i][z] -> WT[((n*128+j)*32+z)*16+i] bf16
//               blocks [512,1024): x transpose tiles -> XW[(j*2+ib)*1024+b][8] bf16
// ---------------------------------------------------------------------------
__global__ __launch_bounds__(256)
void prep(const float* __restrict__ x, const float* __restrict__ W,
          ushort_* __restrict__ XW, ushort_* __restrict__ WT) {
    const int blk = blockIdx.x;
    const int t   = threadIdx.x;

    if (blk < 512) {
        // ---- prep_w (reads coalesced over z, writes 32B/lane contiguous) ----
        const int q  = blk * 256 + t;       // 131072 = 32n*128j*32z
        const int z  = q & 31;
        const int nj = q >> 5;
        const float* p = W + (size_t)nj * (IN_D * DCAP) + z;
        float f[16];
#pragma unroll
        for (int i = 0; i < 16; ++i) f[i] = p[i * 32];
        uint4 lo, hi;
        lo.x = cvt_pk_bf16(f[0],  f[1]);  lo.y = cvt_pk_bf16(f[2],  f[3]);
        lo.z = cvt_pk_bf16(f[4],  f[5]);  lo.w = cvt_pk_bf16(f[6],  f[7]);
        hi.x = cvt_pk_bf16(f[8],  f[9]);  hi.y = cvt_pk_bf16(f[10], f[11]);
        hi.z = cvt_pk_bf16(f[12], f[13]); hi.w = cvt_pk_bf16(f[14], f[15]);
        uint4* dst = (uint4*)(WT + (size_t)q * 16);
        dst[0] = lo; dst[1] = hi;
        return;
    }

    // ---- prep_x: LDS transpose, tile = 64 b x 64 cols (c = j*16+i) ----
    const int id = blk - 512;               // 0..511
    const int tb = id >> 5;                 // 16 b-tiles
    const int tc = id & 31;                 // 32 col-tiles
    const int b0 = tb * 64, c0 = tc * 64;

    __shared__ ushort_ lds[64][72];         // 9 KB, rows 144B (16B-aligned)

    {
        const int c4 = t & 15;
#pragma unroll
        for (int k = 0; k < 4; ++k) {
            const int r = (t >> 4) + 16 * k;
            const float4 f = *(const float4*)(x + (size_t)(b0 + r) * 2048 + c0 + c4 * 4);
            uint2 o;
            o.x = cvt_pk_bf16(f.x, f.y);
            o.y = cvt_pk_bf16(f.z, f.w);
            *(uint2*)&lds[r][c4 * 4] = o;
        }
    }
    __syncthreads();

    const int jb2l = t >> 5;                // 0..7 local output row
    const int jb20 = tc * 8;
#pragma unroll
    for (int h = 0; h < 2; ++h) {
        const int bl = (t & 31) + h * 32;
        bf16x8 v = *(const bf16x8*)&lds[bl][jb2l * 8];
        *(bf16x8*)(XW + ((size_t)(jb20 + jb2l) * 1024 + b0 + bl) * 8) = v;
    }
}

// ---------------------------------------------------------------------------
// kA: block = (n, 32-b tile), 4 waves x 32 j each.
// Phase 1: usum via 4 independent MFMA chains; cross-wave LDS combine.
// Phase 2: recompute u per j (zero acc), dot with usum -> logits bf16.
// ---------------------------------------------------------------------------
__global__ __launch_bounds__(256, 4)
void kA(const ushort_* __restrict__ XW, const ushort_* __restrict__ WT,
        ushort_* __restrict__ LC) {
    const int bid = blockIdx.x;             // 1024 = 32n * 32 btiles
    const int n   = bid >> 5;
    const int cb0 = (bid & 31) * 32;
    const int t   = threadIdx.x;
    const int wv  = t >> 6;                 // 0..3
    const int l   = t & 63;
    const int lo5 = l & 31;
    const int hi  = l >> 5;

    __shared__ float xch[4][16 * 64];       // 16 KB

    const ushort_* aBase = WT + ((size_t)(n * IN_N) * 32 + lo5) * 16 + (size_t)hi * 8;
    const ushort_* bBase = XW + ((size_t)hi * 1024 + cb0 + lo5) * 8;

    const int jbeg = wv * 32;

    f32x16 us0, us1, us2, us3;
#pragma unroll
    for (int r = 0; r < 16; ++r) { us0[r] = 0.f; us1[r] = 0.f; us2[r] = 0.f; us3[r] = 0.f; }

    for (int j = jbeg; j < jbeg + 32; j += 4) {
        bf16x8 a0 = *(const bf16x8*)(aBase + (size_t)j * 512);
        bf16x8 x0 = *(const bf16x8*)(bBase + (size_t)j * 16384);
        bf16x8 a1 = *(const bf16x8*)(aBase + (size_t)(j + 1) * 512);
        bf16x8 x1 = *(const bf16x8*)(bBase + (size_t)(j + 1) * 16384);
        us0 = __builtin_amdgcn_mfma_f32_32x32x16_bf16(a0, x0, us0, 0, 0, 0);
        us1 = __builtin_amdgcn_mfma_f32_32x32x16_bf16(a1, x1, us1, 0, 0, 0);
        bf16x8 a2 = *(const bf16x8*)(aBase + (size_t)(j + 2) * 512);
        bf16x8 x2 = *(const bf16x8*)(bBase + (size_t)(j + 2) * 16384);
        bf16x8 a3 = *(const bf16x8*)(aBase + (size_t)(j + 3) * 512);
        bf16x8 x3 = *(const bf16x8*)(bBase + (size_t)(j + 3) * 16384);
        us2 = __builtin_amdgcn_mfma_f32_32x32x16_bf16(a2, x2, us2, 0, 0, 0);
        us3 = __builtin_amdgcn_mfma_f32_32x32x16_bf16(a3, x3, us3, 0, 0, 0);
    }
#pragma unroll
    for (int r = 0; r < 16; ++r)
        us0[r] = (us0[r] + us1[r]) + (us2[r] + us3[r]);

#pragma unroll
    for (int r = 0; r < 16; ++r) xch[wv][r * 64 + l] = us0[r];
    __syncthreads();

    f32x16 us;
#pragma unroll
    for (int r = 0; r < 16; ++r)
        us[r] = (xch[0][r * 64 + l] + xch[1][r * 64 + l]) +
                (xch[2][r * 64 + l] + xch[3][r * 64 + l]);

    const float rsqD = 0.17677669529663689f;  // 1/sqrt(32)
    f32x16 zc;
#pragma unroll
    for (int r = 0; r < 16; ++r) zc[r] = 0.f;

#pragma unroll 2
    for (int j = jbeg; j < jbeg + 32; ++j) {
        bf16x8 af = *(const bf16x8*)(aBase + (size_t)j * 512);
        bf16x8 xf = *(const bf16x8*)(bBase + (size_t)j * 16384);
        f32x16 u = __builtin_amdgcn_mfma_f32_32x32x16_bf16(af, xf, zc, 0, 0, 0);
        float p0 = u[0] * us[0], p1 = u[1] * us[1];
        float p2 = u[2] * us[2], p3 = u[3] * us[3];
#pragma unroll
        for (int r = 4; r < 16; r += 4) {
            p0 = fmaf(u[r],     us[r],     p0);
            p1 = fmaf(u[r + 1], us[r + 1], p1);
            p2 = fmaf(u[r + 2], us[r + 2], p2);
            p3 = fmaf(u[r + 3], us[r + 3], p3);
        }
        float p = (p0 + p1) + (p2 + p3);
        p += __shfl_xor(p, 32);
        p *= rsqD;
        if (l < 32) {
            uint_ pk = cvt_pk_bf16(p, p);
            LC[(size_t)(n * IN_N + j) * 1024 + cb0 + lo5] = (ushort_)(pk & 0xffffu);
        }
    }
}

// ---------------------------------------------------------------------------
// kB: softmax over n per (b,j), 2 b's per thread (packed uint), + bias.
// ---------------------------------------------------------------------------
__global__ __launch_bounds__(256)
void kB(const float* __restrict__ bias, ushort_* __restrict__ LC) {
    const int t  = blockIdx.x * 256 + threadIdx.x;  // 65536 = 128j * 512 bpair
    const int j  = t >> 9;                           // uniform per block
    const int bp = (t & 511) * 2;
    float vl[NCAP], vh[NCAP];
    float ml = -1e30f, mh = -1e30f;
#pragma unroll
    for (int n = 0; n < NCAP; ++n) {
        const uint_ w = *(const uint_*)(LC + (size_t)(n * IN_N + j) * 1024 + bp);
        vl[n] = bf16_to_f((ushort_)(w & 0xffffu));
        vh[n] = bf16_to_f((ushort_)(w >> 16));
        ml = fmaxf(ml, vl[n]);
        mh = fmaxf(mh, vh[n]);
    }
    float sl = 0.f, sh = 0.f;
#pragma unroll
    for (int n = 0; n < NCAP; ++n) {
        vl[n] = __expf(vl[n] - ml); sl += vl[n];
        vh[n] = __expf(vh[n] - mh); sh += vh[n];
    }
    const float il = 1.f / sl, ih = 1.f / sh;
#pragma unroll
    for (int n = 0; n < NCAP; ++n) {
        const float bb = bias[n * IN_N + j];
        const float cl = vl[n] * il + bb;
        const float ch = vh[n] * ih + bb;
        *(uint_*)(LC + (size_t)(n * IN_N + j) * 1024 + bp) = cvt_pk_bf16(cl, ch);
    }
}

// ---------------------------------------------------------------------------
// kC: s[b,n,z] = sum_j c * u; 4 waves x 32 j, 2 s-chains; wave-0 epilogue.
// ---------------------------------------------------------------------------
__global__ __launch_bounds__(256, 4)
void kC(const ushort_* __restrict__ XW, const ushort_* __restrict__ WT,
        const ushort_* __restrict__ LC, float* __restrict__ out) {
    const int bid = blockIdx.x;
    const int n   = bid >> 5;
    const int cb0 = (bid & 31) * 32;
    const int t   = threadIdx.x;
    const int wv  = t >> 6;
    const int l   = t & 63;
    const int lo5 = l & 31;
    const int hi  = l >> 5;

    __shared__ float xch[3][16 * 64];       // 12 KB

    const ushort_* aBase = WT + ((size_t)(n * IN_N) * 32 + lo5) * 16 + (size_t)hi * 8;
    const ushort_* bBase = XW + ((size_t)hi * 1024 + cb0 + lo5) * 8;
    const ushort_* cBase = LC + (size_t)(n * IN_N) * 1024 + cb0 + lo5;

    f32x16 s0, s1, zc;
#pragma unroll
    for (int r = 0; r < 16; ++r) { s0[r] = 0.f; s1[r] = 0.f; zc[r] = 0.f; }

    const int jbeg = wv * 32;
    for (int j = jbeg; j < jbeg + 32; j += 2) {
        bf16x8 a0 = *(const bf16x8*)(aBase + (size_t)j * 512);
        bf16x8 x0 = *(const bf16x8*)(bBase + (size_t)j * 16384);
        const float c0 = bf16_to_f(cBase[(size_t)j * 1024]);
        bf16x8 a1 = *(const bf16x8*)(aBase + (size_t)(j + 1) * 512);
        bf16x8 x1 = *(const bf16x8*)(bBase + (size_t)(j + 1) * 16384);
        const float c1 = bf16_to_f(cBase[(size_t)(j + 1) * 1024]);
        f32x16 u0 = __builtin_amdgcn_mfma_f32_32x32x16_bf16(a0, x0, zc, 0, 0, 0);
        f32x16 u1 = __builtin_amdgcn_mfma_f32_32x32x16_bf16(a1, x1, zc, 0, 0, 0);
#pragma unroll
        for (int r = 0; r < 16; ++r) {
            s0[r] = fmaf(c0, u0[r], s0[r]);
            s1[r] = fmaf(c1, u1[r], s1[r]);
        }
    }
#pragma unroll
    for (int r = 0; r < 16; ++r) s0[r] += s1[r];

    if (wv > 0) {
#pragma unroll
        for (int r = 0; r < 16; ++r) xch[wv - 1][r * 64 + l] = s0[r];
    }
    __syncthreads();

    if (wv == 0) {
#pragma unroll
        for (int r = 0; r < 16; ++r)
            s0[r] += (xch[0][r * 64 + l] + xch[1][r * 64 + l]) + xch[2][r * 64 + l];
        float q0 = s0[0] * s0[0], q1 = s0[1] * s0[1];
        float q2 = s0[2] * s0[2], q3 = s0[3] * s0[3];
#pragma unroll
        for (int r = 4; r < 16; r += 4) {
            q0 = fmaf(s0[r],     s0[r],     q0);
            q1 = fmaf(s0[r + 1], s0[r + 1], q1);
            q2 = fmaf(s0[r + 2], s0[r + 2], q2);
            q3 = fmaf(s0[r + 3], s0[r + 3], q3);
        }
        float q = (q0 + q1) + (q2 + q3);
        q += __shfl_xor(q, 32);             // other half's 16 z's
        const float nn = sqrtf(q);
        const float f  = (1.f - 1.f / (__expf(nn) + 1e-20f)) / (nn + 1e-20f);
        // lane (lo5,hi), reg r -> z = (r&3) + 8*(r>>2) + 4*hi
        float* op = out + ((size_t)(cb0 + lo5) * NCAP + n) * DCAP + hi * 4;
#pragma unroll
        for (int g = 0; g < 4; ++g) {
            float4 v4 = { s0[g * 4 + 0] * f, s0[g * 4 + 1] * f,
                          s0[g * 4 + 2] * f, s0[g * 4 + 3] * f };
            *(float4*)(op + g * 8) = v4;
        }
    }
}

// ---------------------------------------------------------------------------
extern "C" void kernel_launch(void* const* d_in, const int* in_sizes, int n_in,
                              void* d_out, int out_size, void* d_ws, size_t ws_size,
                              hipStream_t stream) {
    const float* x    = (const float*)d_in[0];   // [1024,128,16]
    const float* W    = (const float*)d_in[1];   // [32,128,16,32]
    const float* bias = (const float*)d_in[2];   // [32,128,1]
    float* out = (float*)d_out;                  // [1024,32,32]

    char* ws = (char*)d_ws;
    ushort_* XW = (ushort_*)ws;                  // 4 MB bf16 x, relaid
    ushort_* WT = (ushort_*)(ws + (4u << 20));   // 4 MB bf16 W^T
    ushort_* LC = (ushort_*)(ws + (8u << 20));   // 8 MB bf16 logits/c

    prep<<<1024, 256, 0, stream>>>(x, W, XW, WT);
    kA<<<1024, 256, 0, stream>>>(XW, WT, LC);
    kB<<<256, 256, 0, stream>>>(bias, LC);
    kC<<<1024, 256, 0, stream>>>(XW, WT, LC, out);
}